// Round 4
// baseline (1911.232 us; speedup 1.0000x reference)
//
#include <hip/hip_runtime.h>
#include <math.h>

// PolaLinearAttention, MI355X round 3: dtype-adaptive.
// R2==R3 NaN despite featurization fix -> input buffers are NOT what I cast
// them to. fp32-read-as-bf16 naturally generates NaN (low mantissa halves have
// uniform exponent fields -> 1/256 are Inf/NaN). Since static evidence is
// ambiguous (test labels say bf16, reference says fp32), detect at runtime:
// k0 scans x's first 4096 u16 words; sane-bf16-exponent fraction ~100% (bf16)
// vs ~57% (fp32). All external loads + final store branch on the flag.
// Intermediates stay bf16. Layout: channel-major T: (b*384+c)*16384 + n.
// ws: flag | km[32][96] f32 | kvm[32][96][48] f32 | qsT,gT,ksT bf16 (~152 MB).
// vT lives at start of d_out (>=50MB under either dtype; dead before k5 writes).

#define NB 4
#define NTOK 16384
#define CDIM 384
#define NHEAD 8
#define HDIM 48
#define IMGH 128
#define IMGW 128

typedef unsigned short u16;

__device__ __forceinline__ float bf2f(u16 u) {
  return __uint_as_float(((unsigned)u) << 16);
}
__device__ __forceinline__ u16 f2bf(float f) {
  unsigned u = __float_as_uint(f);
  u += 0x7FFF + ((u >> 16) & 1);   // RNE
  return (u16)(u >> 16);
}
// |v|^p, safe: never logs non-positive, never inf/NaN.
__device__ __forceinline__ float pow_mag(float r, float p) {
  if (r < 1e-20f) return 0.0f;
  return exp2f(fminf(p * log2f(r), 80.0f));
}
// dual-dtype scalar/vec4 loads for EXTERNAL tensors
__device__ __forceinline__ float ldx1(const void* p, size_t i, bool f32) {
  return f32 ? ((const float*)p)[i] : bf2f(((const u16*)p)[i]);
}
__device__ __forceinline__ void ldx4(const void* p, size_t i, bool f32, float o[4]) {
  if (f32) {
    float4 v = *(const float4*)((const float*)p + i);
    o[0]=v.x; o[1]=v.y; o[2]=v.z; o[3]=v.w;
  } else {
    ushort4 v = *(const ushort4*)((const u16*)p + i);
    o[0]=bf2f(v.x); o[1]=bf2f(v.y); o[2]=bf2f(v.z); o[3]=bf2f(v.w);
  }
}

// ---------------- k0: dtype detector -------------------------------------------------
__global__ __launch_bounds__(256) void k0_detect(const void* __restrict__ x,
                                                 int* __restrict__ flag) {
  __shared__ int s[256];
  const u16* p = (const u16*)x;
  const int t = threadIdx.x;
  int good = 0;
#pragma unroll
  for (int i = 0; i < 16; ++i) {
    const u16 w = p[t * 16 + i];
    const int e = (w >> 7) & 0xFF;          // bf16 exponent field
    good += (e >= 0x60 && e <= 0x85) ? 1 : 0;  // |v| in [2^-31, 2^6]
  }
  s[t] = good;
  __syncthreads();
  for (int o = 128; o > 0; o >>= 1) {
    if (t < o) s[t] += s[t + o];
    __syncthreads();
  }
  if (t == 0) *flag = (s[0] >= (4096 * 4) / 5) ? 0 : 1;  // 0 = bf16, 1 = fp32
}

// ---------------- k1: x @ [W_qg | W_kv] -> qsT,gT,ksT (ws) + vT (d_out) -------------
__global__ __launch_bounds__(256) void k1_gemm_qgkv(
    const void* __restrict__ x, const void* __restrict__ Wqg, const void* __restrict__ Wkv,
    const void* __restrict__ pos_enc, const void* __restrict__ scale_p,
    const int* __restrict__ flag,
    u16* __restrict__ qsT, u16* __restrict__ gT, u16* __restrict__ ksT, u16* __restrict__ vT)
{
  const bool f32 = (*flag != 0);
  __shared__ __align__(16) float As[16][68];  // [k][m], padded
  __shared__ __align__(16) float Bs[16][68];  // [k][n]
  const int n0 = blockIdx.x * 64;             // 0..1535
  const int m0 = blockIdx.y * 64;
  const int t  = threadIdx.x;
  const int tx = t & 15, ty = t >> 4;

  const void* Bmat = (n0 < 768) ? Wqg : Wkv;
  const int bn0 = (n0 < 768) ? n0 : (n0 - 768);

  const int ar = t >> 2, akq = t & 3;    // A: 64 rows x 16 k, vec4 along k
  const int bkr = t >> 4, bnq = t & 15;  // B: 16 k x 64 n, vec4 along n

  float acc[4][4] = {};
  for (int k0 = 0; k0 < CDIM; k0 += 16) {
    float a4[4], b4[4];
    ldx4(x,    (size_t)(m0 + ar) * CDIM + k0 + akq * 4, f32, a4);
    ldx4(Bmat, (size_t)(k0 + bkr) * 768 + bn0 + bnq * 4, f32, b4);
    As[akq*4+0][ar] = a4[0];
    As[akq*4+1][ar] = a4[1];
    As[akq*4+2][ar] = a4[2];
    As[akq*4+3][ar] = a4[3];
    Bs[bkr][bnq*4+0] = b4[0];
    Bs[bkr][bnq*4+1] = b4[1];
    Bs[bkr][bnq*4+2] = b4[2];
    Bs[bkr][bnq*4+3] = b4[3];
    __syncthreads();
#pragma unroll
    for (int kk = 0; kk < 16; ++kk) {
      float4 av = *(const float4*)&As[kk][ty*4];
      float4 bv = *(const float4*)&Bs[kk][tx*4];
      float aa[4] = {av.x, av.y, av.z, av.w};
      float bb[4] = {bv.x, bv.y, bv.z, bv.w};
#pragma unroll
      for (int i = 0; i < 4; ++i)
#pragma unroll
        for (int j = 0; j < 4; ++j)
          acc[i][j] = fmaf(aa[i], bb[j], acc[i][j]);
    }
    __syncthreads();
  }
  const int b    = m0 >> 14;
  const int tok0 = (m0 & (NTOK - 1)) + ty * 4;
#pragma unroll
  for (int j = 0; j < 4; ++j) {
    const int gj = n0 + tx*4 + j;          // region uniform per block (n0 mult of 64)
    const int region = gj / CDIM;
    const int c = gj % CDIM;
    const size_t base = ((size_t)(b * CDIM + c)) * NTOK + tok0;
    const float v0 = acc[0][j], v1 = acc[1][j], v2 = acc[2][j], v3 = acc[3][j];
    if (region == 0) {
      const float inv = 1.0f / log1pf(expf(ldx1(scale_p, c, f32)));
      *(ushort4*)(qsT + base) =
          make_ushort4(f2bf(v0*inv), f2bf(v1*inv), f2bf(v2*inv), f2bf(v3*inv));
    } else if (region == 1) {
      *(ushort4*)(gT + base) = make_ushort4(f2bf(v0), f2bf(v1), f2bf(v2), f2bf(v3));
    } else if (region == 2) {
      const float inv = 1.0f / log1pf(expf(ldx1(scale_p, c, f32)));
      const float p0 = ldx1(pos_enc, (size_t)(tok0+0)*CDIM + c, f32);
      const float p1 = ldx1(pos_enc, (size_t)(tok0+1)*CDIM + c, f32);
      const float p2 = ldx1(pos_enc, (size_t)(tok0+2)*CDIM + c, f32);
      const float p3 = ldx1(pos_enc, (size_t)(tok0+3)*CDIM + c, f32);
      *(ushort4*)(ksT + base) = make_ushort4(f2bf((v0+p0)*inv), f2bf((v1+p1)*inv),
                                             f2bf((v2+p2)*inv), f2bf((v3+p3)*inv));
    } else {
      *(ushort4*)(vT + base) = make_ushort4(f2bf(v0), f2bf(v1), f2bf(v2), f2bf(v3));
    }
  }
}

// ---------------- k2: per (b,h): km[96] = mean(kk), kvm[96][48] = kk^T v / N -------
__global__ __launch_bounds__(256) void k2_stats(
    const u16* __restrict__ ksT, const u16* __restrict__ vT,
    const void* __restrict__ power_p, const int* __restrict__ flag,
    float* __restrict__ km, float* __restrict__ kvm)
{
  const bool f32 = (*flag != 0);
  __shared__ float kkL[96][65];   // featurized k tile [d][nn], +1 pad
  __shared__ float vL[48][65];
  __shared__ float pw[48];
  const int bh = blockIdx.x;                 // 0..31
  const int b = bh >> 3, h = bh & 7;
  const int t = threadIdx.x;
  if (t < 48) pw[t] = 1.0f + 4.0f / (1.0f + expf(-ldx1(power_p, h*HDIM + t, f32)));
  __syncthreads();
  const int td = t & 15, te = t >> 4;        // 16x16 threads, 6x3 cells -> 96x48
  float acc[6][3] = {};
  float ksum = 0.0f;
  const u16* ksbase = ksT + ((size_t)(b*CDIM + h*HDIM)) * NTOK;
  const u16* vbase  = vT  + ((size_t)(b*CDIM + h*HDIM)) * NTOK;
  const int n0base = blockIdx.y * 1024;      // 16-way K split
  for (int tile = 0; tile < 16; ++tile) {
    const int n0 = n0base + tile*64;
    for (int i = t; i < 48*16; i += 256) {   // 48 rows x 16 ushort4 quads
      const int c = i >> 4, qd = (i & 15) * 4;
      ushort4 kq = *(const ushort4*)(ksbase + (size_t)c*NTOK + n0 + qd);
      ushort4 vq = *(const ushort4*)(vbase  + (size_t)c*NTOK + n0 + qd);
      const float p = pw[c];
      float kf[4] = {bf2f(kq.x), bf2f(kq.y), bf2f(kq.z), bf2f(kq.w)};
      float vf[4] = {bf2f(vq.x), bf2f(vq.y), bf2f(vq.z), bf2f(vq.w)};
#pragma unroll
      for (int jj = 0; jj < 4; ++jj) {
        const float f = pow_mag(fabsf(kf[jj]), p);
        kkL[c][qd+jj]    = (kf[jj] > 0.f) ? f : 0.f;
        kkL[c+48][qd+jj] = (kf[jj] < 0.f) ? f : 0.f;
        vL[c][qd+jj] = vf[jj];
      }
    }
    __syncthreads();
#pragma unroll 2
    for (int nn = 0; nn < 64; ++nn) {
      float av[6], bv[3];
#pragma unroll
      for (int i = 0; i < 6; ++i) av[i] = kkL[td*6+i][nn];
#pragma unroll
      for (int j = 0; j < 3; ++j) bv[j] = vL[te*3+j][nn];
#pragma unroll
      for (int i = 0; i < 6; ++i)
#pragma unroll
        for (int j = 0; j < 3; ++j)
          acc[i][j] = fmaf(av[i], bv[j], acc[i][j]);
    }
    if (t < 96) {
#pragma unroll 4
      for (int nn = 0; nn < 64; ++nn) ksum += kkL[t][nn];
    }
    __syncthreads();
  }
  const float inv_n = 1.0f / (float)NTOK;
#pragma unroll
  for (int i = 0; i < 6; ++i)
#pragma unroll
    for (int j = 0; j < 3; ++j)
      atomicAdd(&kvm[(size_t)bh*96*48 + (td*6+i)*48 + (te*3+j)], acc[i][j]*inv_n);
  if (t < 96) atomicAdd(&km[bh*96 + t], ksum*inv_n);
}

// ---------------- k3: q features, z-norm, x_sim/x_opp; q from qsT, attn -> ksT ----
__global__ __launch_bounds__(256) void k3_attn(
    const u16* __restrict__ qsT, u16* __restrict__ attnT,   // attnT = ksT (dead after k2)
    const float* __restrict__ km_g, const float* __restrict__ kvm_g,
    const void* __restrict__ power_p, const int* __restrict__ flag)
{
  const bool f32 = (*flag != 0);
  __shared__ __align__(16) float kvmL[96][48];
  __shared__ float kmL[96];
  __shared__ float pw[48];
  const int bh = blockIdx.y;
  const int b = bh >> 3, h = bh & 7;
  const int t = threadIdx.x;
  for (int i = t; i < 96*48; i += 256) kvmL[i/48][i%48] = kvm_g[(size_t)bh*96*48 + i];
  if (t < 96) kmL[t] = km_g[bh*96 + t];
  if (t < 48) pw[t] = 1.0f + 4.0f/(1.0f + expf(-ldx1(power_p, h*HDIM + t, f32)));
  __syncthreads();
  const int n = blockIdx.x * 512 + t;        // tokens n and n+256
  const size_t chan0 = ((size_t)(b*CDIM + h*HDIM)) * NTOK + n;
  const u16* qbase = qsT + chan0;
  u16* obase = attnT + chan0;
  float4 accs[2][6] = {}, acco[2][6] = {};
  float zs[2] = {}, zo[2] = {};
  for (int d = 0; d < 48; ++d) {
    const float p = pw[d];
    float qp[2], qn[2];
#pragma unroll
    for (int i = 0; i < 2; ++i) {
      const float qv = bf2f(qbase[(size_t)d*NTOK + i*256]);
      const float f = pow_mag(fabsf(qv), p);
      qp[i] = (qv > 0.f) ? f : 0.f;
      qn[i] = (qv < 0.f) ? f : 0.f;
      zs[i] = fmaf(qp[i], kmL[d], zs[i]); zs[i] = fmaf(qn[i], kmL[d+48], zs[i]);
      zo[i] = fmaf(qn[i], kmL[d], zo[i]); zo[i] = fmaf(qp[i], kmL[d+48], zo[i]);
    }
#pragma unroll
    for (int e4 = 0; e4 < 6; ++e4) {
      const float4 kvA = *(const float4*)&kvmL[d]   [e4*4];      // sim, q_pos side
      const float4 kvB = *(const float4*)&kvmL[d+48][e4*4];      // sim, q_neg side
      const float4 kvC = *(const float4*)&kvmL[d]   [24+e4*4];   // opp
      const float4 kvD = *(const float4*)&kvmL[d+48][24+e4*4];
#pragma unroll
      for (int i = 0; i < 2; ++i) {
        accs[i][e4].x = fmaf(qp[i], kvA.x, fmaf(qn[i], kvB.x, accs[i][e4].x));
        accs[i][e4].y = fmaf(qp[i], kvA.y, fmaf(qn[i], kvB.y, accs[i][e4].y));
        accs[i][e4].z = fmaf(qp[i], kvA.z, fmaf(qn[i], kvB.z, accs[i][e4].z));
        accs[i][e4].w = fmaf(qp[i], kvA.w, fmaf(qn[i], kvB.w, accs[i][e4].w));
        acco[i][e4].x = fmaf(qn[i], kvC.x, fmaf(qp[i], kvD.x, acco[i][e4].x));
        acco[i][e4].y = fmaf(qn[i], kvC.y, fmaf(qp[i], kvD.y, acco[i][e4].y));
        acco[i][e4].z = fmaf(qn[i], kvC.z, fmaf(qp[i], kvD.z, acco[i][e4].z));
        acco[i][e4].w = fmaf(qn[i], kvC.w, fmaf(qp[i], kvD.w, acco[i][e4].w));
      }
    }
  }
#pragma unroll
  for (int i = 0; i < 2; ++i) {
    const float zsi = 1.0f/(zs[i] + 1e-6f);
    const float zoi = 1.0f/(zo[i] + 1e-6f);
#pragma unroll
    for (int e4 = 0; e4 < 6; ++e4) {
      const float4 s = accs[i][e4], o = acco[i][e4];
      obase[(size_t)(e4*4+0)*NTOK + i*256]      = f2bf(s.x*zsi);
      obase[(size_t)(e4*4+1)*NTOK + i*256]      = f2bf(s.y*zsi);
      obase[(size_t)(e4*4+2)*NTOK + i*256]      = f2bf(s.z*zsi);
      obase[(size_t)(e4*4+3)*NTOK + i*256]      = f2bf(s.w*zsi);
      obase[(size_t)(24+e4*4+0)*NTOK + i*256]   = f2bf(o.x*zoi);
      obase[(size_t)(24+e4*4+1)*NTOK + i*256]   = f2bf(o.y*zoi);
      obase[(size_t)(24+e4*4+2)*NTOK + i*256]   = f2bf(o.z*zoi);
      obase[(size_t)(24+e4*4+3)*NTOK + i*256]   = f2bf(o.w*zoi);
    }
  }
}

// ---------------- k4: 5x5 depthwise conv on vT + out2 = (attn + conv) * g ----------
__global__ __launch_bounds__(256) void k4_conv_combine(
    const u16* __restrict__ vT, const u16* __restrict__ gT,
    const void* __restrict__ dwc_w, const void* __restrict__ dwc_b,
    const int* __restrict__ flag,
    u16* __restrict__ attnT)   // in/out (= ksT)
{
  const bool f32 = (*flag != 0);
  __shared__ float tile[20][128];   // 16-row strip + 2 halo each side
  const int bc = blockIdx.y;        // 0..1535 = b*384 + c
  const int y0 = blockIdx.x * 16;
  const int t = threadIdx.x;
  const int d = bc % 48;            // channel within head-dim (48 | 384)
  float w[25];
#pragma unroll
  for (int i = 0; i < 25; ++i) w[i] = ldx1(dwc_w, d*25 + i, f32);
  const float bias = ldx1(dwc_b, d, f32);
  const u16* vimg = vT + (size_t)bc * NTOK;
  for (int i = t; i < 20*128; i += 256) {
    const int r = i >> 7, xx = i & 127;
    const int gy = y0 + r - 2;
    tile[r][xx] = (gy >= 0 && gy < IMGH) ? bf2f(vimg[gy*IMGW + xx]) : 0.f;
  }
  __syncthreads();
  u16* abase = attnT + (size_t)bc * NTOK;
  const u16* gbase = gT + (size_t)bc * NTOK;
#pragma unroll
  for (int k = 0; k < 8; ++k) {
    const int px = t + k*256;
    const int yy = px >> 7, xcol = px & 127;
    float acc = bias;
#pragma unroll
    for (int dy = 0; dy < 5; ++dy)
#pragma unroll
      for (int dx = 0; dx < 5; ++dx) {
        const int ux = xcol + dx - 2;
        const float val = (ux >= 0 && ux < IMGW) ? tile[yy+dy][ux] : 0.f;
        acc = fmaf(w[dy*5+dx], val, acc);
      }
    const int gidx = (y0 + yy)*IMGW + xcol;
    abase[gidx] = f2bf((bf2f(abase[gidx]) + acc) * bf2f(gbase[gidx]));
  }
}

// ---------------- k5: out2T^T @ W_proj + b_proj -> d_out (B,N,C) -------------------
__global__ __launch_bounds__(256) void k5_gemm_proj(
    const u16* __restrict__ AT,   // (b*384+k)*16384 + n  (= ksT)
    const void* __restrict__ Wp, const void* __restrict__ bp,
    const int* __restrict__ flag,
    void* __restrict__ out)
{
  const bool f32 = (*flag != 0);
  __shared__ __align__(16) float As[16][68];
  __shared__ __align__(16) float Bs[16][68];
  const int n0 = blockIdx.x * 64;   // 0..383
  const int m0 = blockIdx.y * 64;
  const int t = threadIdx.x;
  const int tx = t & 15, ty = t >> 4;
  const int b = m0 >> 14;
  const int tok0 = m0 & (NTOK - 1);
  const int akk = t >> 4, arq = t & 15;
  const int bkr = t >> 4, bnq = t & 15;
  const u16* Abase = AT + (size_t)b*CDIM*NTOK + tok0;
  float acc[4][4] = {};
  for (int k0 = 0; k0 < CDIM; k0 += 16) {
    ushort4 a4 = *(const ushort4*)(Abase + (size_t)(k0 + akk)*NTOK + arq*4);
    float b4[4];
    ldx4(Wp, (size_t)(k0 + bkr)*CDIM + n0 + bnq*4, f32, b4);
    As[akk][arq*4+0] = bf2f(a4.x);
    As[akk][arq*4+1] = bf2f(a4.y);
    As[akk][arq*4+2] = bf2f(a4.z);
    As[akk][arq*4+3] = bf2f(a4.w);
    Bs[bkr][bnq*4+0] = b4[0];
    Bs[bkr][bnq*4+1] = b4[1];
    Bs[bkr][bnq*4+2] = b4[2];
    Bs[bkr][bnq*4+3] = b4[3];
    __syncthreads();
#pragma unroll
    for (int kk = 0; kk < 16; ++kk) {
      float4 av = *(const float4*)&As[kk][ty*4];
      float4 bv = *(const float4*)&Bs[kk][tx*4];
      float aa[4] = {av.x, av.y, av.z, av.w};
      float bb[4] = {bv.x, bv.y, bv.z, bv.w};
#pragma unroll
      for (int i = 0; i < 4; ++i)
#pragma unroll
        for (int j = 0; j < 4; ++j)
          acc[i][j] = fmaf(aa[i], bb[j], acc[i][j]);
    }
    __syncthreads();
  }
  const float bb0 = ldx1(bp, n0 + tx*4 + 0, f32), bb1 = ldx1(bp, n0 + tx*4 + 1, f32);
  const float bb2 = ldx1(bp, n0 + tx*4 + 2, f32), bb3 = ldx1(bp, n0 + tx*4 + 3, f32);
#pragma unroll
  for (int i = 0; i < 4; ++i) {
    const int m = m0 + ty*4 + i;   // row in (B*N)
    const size_t oidx = (size_t)m*CDIM + n0 + tx*4;
    if (f32) {
      *(float4*)((float*)out + oidx) =
          make_float4(acc[i][0]+bb0, acc[i][1]+bb1, acc[i][2]+bb2, acc[i][3]+bb3);
    } else {
      *(ushort4*)((u16*)out + oidx) =
          make_ushort4(f2bf(acc[i][0]+bb0), f2bf(acc[i][1]+bb1),
                       f2bf(acc[i][2]+bb2), f2bf(acc[i][3]+bb3));
    }
  }
}

extern "C" void kernel_launch(void* const* d_in, const int* in_sizes, int n_in,
                              void* d_out, int out_size, void* d_ws, size_t ws_size,
                              hipStream_t stream) {
  const void* x       = d_in[0];
  const void* Wqg     = d_in[1];
  const void* Wkv     = d_in[2];
  const void* Wproj   = d_in[3];
  const void* bproj   = d_in[4];
  const void* pos_enc = d_in[5];
  const void* power_p = d_in[6];
  const void* scale_p = d_in[7];
  const void* dwc_w   = d_in[8];
  const void* dwc_b   = d_in[9];

  const size_t S = (size_t)NB * NTOK * CDIM;            // 25,165,824 elements
  const size_t stats_off   = 256;                        // flag + pad
  const size_t stats_bytes = (size_t)(32*96 + 32*96*48) * sizeof(float);  // 602112
  const size_t need = stats_off + stats_bytes + 3 * S * sizeof(u16);      // ~152 MB
  if (ws_size < need) return;  // clean absmax-fail beats a memory fault

  int*   flag = (int*)d_ws;
  float* km   = (float*)((char*)d_ws + stats_off);       // [32][96]
  float* kvm  = km + 32*96;                              // [32][96][48]
  u16* qsT = (u16*)((char*)d_ws + stats_off + stats_bytes);  // q/softplus(scale)
  u16* gT  = qsT + S;
  u16* ksT = gT + S;                                     // k feats; then attn; then out2
  u16* vT  = (u16*)d_out;                                // dead before k5 writes

  hipMemsetAsync(km, 0, stats_bytes, stream);

  k0_detect<<<1, 256, 0, stream>>>(x, flag);
  k1_gemm_qgkv<<<dim3(24, 1024), 256, 0, stream>>>(x, Wqg, Wkv, pos_enc, scale_p,
                                                   flag, qsT, gT, ksT, vT);
  k2_stats<<<dim3(32, 16), 256, 0, stream>>>(ksT, vT, power_p, flag, km, kvm);
  k3_attn<<<dim3(32, 32), 256, 0, stream>>>(qsT, ksT, km, kvm, power_p, flag);
  k4_conv_combine<<<dim3(8, 1536), 256, 0, stream>>>(vT, gT, dwc_w, dwc_b, flag, ksT);
  k5_gemm_proj<<<dim3(6, 1024), 256, 0, stream>>>(ksT, Wproj, bproj, flag, d_out);
}

// Round 5
// 866.253 us; speedup vs baseline: 2.2063x; 2.2063x over previous
//
#include <hip/hip_runtime.h>
#include <math.h>

// PolaLinearAttention, MI355X round 5: MFMA bf16 GEMMs for k1 and k5.
// R4 counters: k1 fp32-VALU GEMM = 1155us, VALUBusy 91%, MfmaUtil 0 -> move
// both big GEMMs to v_mfma_f32_16x16x32_bf16 (128x128 tile, BK=64, m97-style).
// Dual-dtype (runtime-detected fp32/bf16) external loads kept from R4.
// Layout: intermediates channel-major T: (b*384+c)*16384 + n (bf16).
//   qsT,gT,ksT in ws; vT in d_out (dead before k5 writes).
//   prep: W2T[1536][384]=[Wqg|Wkv]^T bf16, WpT[384][384]=Wproj^T bf16.
//   k4b transposes out2 (ksT, channel-major) -> token-major into qsT (dead).
// ws: flag|stats(0.6MB)|qsT,gT,ksT(151MB)|W2T,WpT(1.5MB) ~= 154MB (guarded).

#define NB 4
#define NTOK 16384
#define CDIM 384
#define NHEAD 8
#define HDIM 48
#define IMGH 128
#define IMGW 128

typedef unsigned short u16;
typedef __attribute__((ext_vector_type(8))) short bf16x8;
typedef __attribute__((ext_vector_type(4))) float f32x4;

__device__ __forceinline__ float bf2f(u16 u) {
  return __uint_as_float(((unsigned)u) << 16);
}
__device__ __forceinline__ u16 f2bf(float f) {
  unsigned u = __float_as_uint(f);
  u += 0x7FFF + ((u >> 16) & 1);   // RNE
  return (u16)(u >> 16);
}
// |v|^p, safe: never logs non-positive, never inf/NaN.
__device__ __forceinline__ float pow_mag(float r, float p) {
  if (r < 1e-20f) return 0.0f;
  return exp2f(fminf(p * log2f(r), 80.0f));
}
// dual-dtype loads for EXTERNAL tensors
__device__ __forceinline__ float ldx1(const void* p, size_t i, bool f32) {
  return f32 ? ((const float*)p)[i] : bf2f(((const u16*)p)[i]);
}

// ---------------- k0: dtype detector ------------------------------------------------
__global__ __launch_bounds__(256) void k0_detect(const void* __restrict__ x,
                                                 int* __restrict__ flag) {
  __shared__ int s[256];
  const u16* p = (const u16*)x;
  const int t = threadIdx.x;
  int good = 0;
#pragma unroll
  for (int i = 0; i < 16; ++i) {
    const u16 w = p[t * 16 + i];
    const int e = (w >> 7) & 0xFF;
    good += (e >= 0x60 && e <= 0x85) ? 1 : 0;   // sane bf16 exponent
  }
  s[t] = good;
  __syncthreads();
  for (int o = 128; o > 0; o >>= 1) {
    if (t < o) s[t] += s[t + o];
    __syncthreads();
  }
  if (t == 0) *flag = (s[0] >= (4096 * 4) / 5) ? 0 : 1;  // 0 = bf16, 1 = fp32
}

// ---------------- kprep: bf16 transposed weights -----------------------------------
__global__ __launch_bounds__(256) void kprep(
    const void* __restrict__ Wqg, const void* __restrict__ Wkv,
    const void* __restrict__ Wp, const int* __restrict__ flag,
    u16* __restrict__ W2T, u16* __restrict__ WpT)
{
  const bool f32 = (*flag != 0);
  const int idx = blockIdx.x * 256 + threadIdx.x;
  if (idx < 1536 * 384) {
    const int n = idx / 384, k = idx - n * 384;
    const float v = (n < 768) ? ldx1(Wqg, (size_t)k * 768 + n, f32)
                              : ldx1(Wkv, (size_t)k * 768 + (n - 768), f32);
    W2T[idx] = f2bf(v);
  } else {
    const int j = idx - 1536 * 384;
    if (j < 384 * 384) {
      const int n = j / 384, k = j - n * 384;
      WpT[j] = f2bf(ldx1(Wp, (size_t)k * 384 + n, f32));
    }
  }
}

// ---------------- k1: MFMA GEMM x @ [Wqg|Wkv] -> qsT,gT,ksT,vT ---------------------
// 128(M tok) x 128(N ch) tile, BK=64, 4 waves each 64x64; XOR-swizzled LDS chunks.
__global__ __launch_bounds__(256) void k1_mfma(
    const void* __restrict__ x, const u16* __restrict__ W2T,
    const void* __restrict__ pos_enc, const void* __restrict__ scale_p,
    const int* __restrict__ flag,
    u16* __restrict__ qsT, u16* __restrict__ gT, u16* __restrict__ ksT, u16* __restrict__ vT)
{
  const bool f32 = (*flag != 0);
  __shared__ __align__(16) u16 Asm[128 * 64];   // [m][k]
  __shared__ __align__(16) u16 Bsm[128 * 64];   // [n][k]
  const int t = threadIdx.x;
  const int n0 = blockIdx.x * 128;              // 0..1535
  const int m0 = blockIdx.y * 128;              // 0..65535
  const int wave = t >> 6, lane = t & 63;
  const int wr = wave >> 1, wc = wave & 1;
  const int lm = lane & 15, lq = lane >> 4;

  f32x4 acc[4][4] = {};

  for (int k0 = 0; k0 < CDIM; k0 += 64) {
#pragma unroll
    for (int i = 0; i < 4; ++i) {
      const int chunk = t + i * 256;            // 1024 chunks of 8 u16
      const int row = chunk >> 3, c8 = chunk & 7;
      const int ldsoff = row * 64 + ((c8 ^ (row & 7)) * 8);
      if (f32) {
        const float* xp = (const float*)x + (size_t)(m0 + row) * CDIM + k0 + c8 * 8;
        const float4 v0 = *(const float4*)xp;
        const float4 v1 = *(const float4*)(xp + 4);
        *(ushort4*)&Asm[ldsoff]     = make_ushort4(f2bf(v0.x), f2bf(v0.y), f2bf(v0.z), f2bf(v0.w));
        *(ushort4*)&Asm[ldsoff + 4] = make_ushort4(f2bf(v1.x), f2bf(v1.y), f2bf(v1.z), f2bf(v1.w));
      } else {
        *(uint4*)&Asm[ldsoff] =
            *(const uint4*)((const u16*)x + (size_t)(m0 + row) * CDIM + k0 + c8 * 8);
      }
      *(uint4*)&Bsm[ldsoff] = *(const uint4*)(W2T + (size_t)(n0 + row) * CDIM + k0 + c8 * 8);
    }
    __syncthreads();
#pragma unroll
    for (int kh = 0; kh < 2; ++kh) {
      bf16x8 af[4], bfr[4];
#pragma unroll
      for (int r = 0; r < 4; ++r) {
        const int row = wr * 64 + r * 16 + lm;
        af[r] = *(const bf16x8*)&Asm[row * 64 + (((kh * 4 + lq) ^ (row & 7)) * 8)];
      }
#pragma unroll
      for (int cb = 0; cb < 4; ++cb) {
        const int row = wc * 64 + cb * 16 + lm;
        bfr[cb] = *(const bf16x8*)&Bsm[row * 64 + (((kh * 4 + lq) ^ (row & 7)) * 8)];
      }
#pragma unroll
      for (int r = 0; r < 4; ++r)
#pragma unroll
        for (int cb = 0; cb < 4; ++cb)
          acc[r][cb] = __builtin_amdgcn_mfma_f32_16x16x32_bf16(af[r], bfr[cb], acc[r][cb], 0, 0, 0);
    }
    __syncthreads();
  }
  // epilogue: C/D layout col=lane&15 (=n), row=(lane>>4)*4+reg (=token)
  const int b = m0 >> 14;
  const int region = n0 / CDIM;                 // uniform per block (384 = 3*128)
#pragma unroll
  for (int cb = 0; cb < 4; ++cb) {
    const int cg = n0 + wc * 64 + cb * 16 + lm;
    const int c = cg - region * CDIM;
    float inv = 1.0f;
    if (region == 0 || region == 2) inv = 1.0f / log1pf(expf(ldx1(scale_p, c, f32)));
#pragma unroll
    for (int r = 0; r < 4; ++r) {
      const int tok = (m0 & (NTOK - 1)) + wr * 64 + r * 16 + lq * 4;
      const size_t base = ((size_t)(b * CDIM + c)) * NTOK + tok;
      const f32x4 v = acc[r][cb];
      if (region == 0) {
        *(ushort4*)(qsT + base) =
            make_ushort4(f2bf(v[0] * inv), f2bf(v[1] * inv), f2bf(v[2] * inv), f2bf(v[3] * inv));
      } else if (region == 1) {
        *(ushort4*)(gT + base) = make_ushort4(f2bf(v[0]), f2bf(v[1]), f2bf(v[2]), f2bf(v[3]));
      } else if (region == 2) {
        const float p0 = ldx1(pos_enc, (size_t)(tok + 0) * CDIM + c, f32);
        const float p1 = ldx1(pos_enc, (size_t)(tok + 1) * CDIM + c, f32);
        const float p2 = ldx1(pos_enc, (size_t)(tok + 2) * CDIM + c, f32);
        const float p3 = ldx1(pos_enc, (size_t)(tok + 3) * CDIM + c, f32);
        *(ushort4*)(ksT + base) = make_ushort4(f2bf((v[0] + p0) * inv), f2bf((v[1] + p1) * inv),
                                               f2bf((v[2] + p2) * inv), f2bf((v[3] + p3) * inv));
      } else {
        *(ushort4*)(vT + base) = make_ushort4(f2bf(v[0]), f2bf(v[1]), f2bf(v[2]), f2bf(v[3]));
      }
    }
  }
}

// ---------------- k2: per (b,h): km[96] = mean(kk), kvm[96][48] = kk^T v / N -------
__global__ __launch_bounds__(256) void k2_stats(
    const u16* __restrict__ ksT, const u16* __restrict__ vT,
    const void* __restrict__ power_p, const int* __restrict__ flag,
    float* __restrict__ km, float* __restrict__ kvm)
{
  const bool f32 = (*flag != 0);
  __shared__ float kkL[96][65];
  __shared__ float vL[48][65];
  __shared__ float pw[48];
  const int bh = blockIdx.x;
  const int b = bh >> 3, h = bh & 7;
  const int t = threadIdx.x;
  if (t < 48) pw[t] = 1.0f + 4.0f / (1.0f + expf(-ldx1(power_p, h * HDIM + t, f32)));
  __syncthreads();
  const int td = t & 15, te = t >> 4;
  float acc[6][3] = {};
  float ksum = 0.0f;
  const u16* ksbase = ksT + ((size_t)(b * CDIM + h * HDIM)) * NTOK;
  const u16* vbase  = vT  + ((size_t)(b * CDIM + h * HDIM)) * NTOK;
  const int n0base = blockIdx.y * 1024;
  for (int tile = 0; tile < 16; ++tile) {
    const int n0 = n0base + tile * 64;
    for (int i = t; i < 48 * 16; i += 256) {
      const int c = i >> 4, qd = (i & 15) * 4;
      ushort4 kq = *(const ushort4*)(ksbase + (size_t)c * NTOK + n0 + qd);
      ushort4 vq = *(const ushort4*)(vbase  + (size_t)c * NTOK + n0 + qd);
      const float p = pw[c];
      float kf[4] = {bf2f(kq.x), bf2f(kq.y), bf2f(kq.z), bf2f(kq.w)};
      float vf[4] = {bf2f(vq.x), bf2f(vq.y), bf2f(vq.z), bf2f(vq.w)};
#pragma unroll
      for (int jj = 0; jj < 4; ++jj) {
        const float f = pow_mag(fabsf(kf[jj]), p);
        kkL[c][qd + jj]      = (kf[jj] > 0.f) ? f : 0.f;
        kkL[c + 48][qd + jj] = (kf[jj] < 0.f) ? f : 0.f;
        vL[c][qd + jj] = vf[jj];
      }
    }
    __syncthreads();
#pragma unroll 2
    for (int nn = 0; nn < 64; ++nn) {
      float av[6], bv[3];
#pragma unroll
      for (int i = 0; i < 6; ++i) av[i] = kkL[td * 6 + i][nn];
#pragma unroll
      for (int j = 0; j < 3; ++j) bv[j] = vL[te * 3 + j][nn];
#pragma unroll
      for (int i = 0; i < 6; ++i)
#pragma unroll
        for (int j = 0; j < 3; ++j)
          acc[i][j] = fmaf(av[i], bv[j], acc[i][j]);
    }
    if (t < 96) {
#pragma unroll 4
      for (int nn = 0; nn < 64; ++nn) ksum += kkL[t][nn];
    }
    __syncthreads();
  }
  const float inv_n = 1.0f / (float)NTOK;
#pragma unroll
  for (int i = 0; i < 6; ++i)
#pragma unroll
    for (int j = 0; j < 3; ++j)
      atomicAdd(&kvm[(size_t)bh * 96 * 48 + (td * 6 + i) * 48 + (te * 3 + j)], acc[i][j] * inv_n);
  if (t < 96) atomicAdd(&km[bh * 96 + t], ksum * inv_n);
}

// ---------------- k3: q features, z-norm, x_sim/x_opp; attn -> ksT -----------------
__global__ __launch_bounds__(256) void k3_attn(
    const u16* __restrict__ qsT, u16* __restrict__ attnT,
    const float* __restrict__ km_g, const float* __restrict__ kvm_g,
    const void* __restrict__ power_p, const int* __restrict__ flag)
{
  const bool f32 = (*flag != 0);
  __shared__ __align__(16) float kvmL[96][48];
  __shared__ float kmL[96];
  __shared__ float pw[48];
  const int bh = blockIdx.y;
  const int b = bh >> 3, h = bh & 7;
  const int t = threadIdx.x;
  for (int i = t; i < 96 * 48; i += 256) kvmL[i / 48][i % 48] = kvm_g[(size_t)bh * 96 * 48 + i];
  if (t < 96) kmL[t] = km_g[bh * 96 + t];
  if (t < 48) pw[t] = 1.0f + 4.0f / (1.0f + expf(-ldx1(power_p, h * HDIM + t, f32)));
  __syncthreads();
  const int n = blockIdx.x * 512 + t;
  const size_t chan0 = ((size_t)(b * CDIM + h * HDIM)) * NTOK + n;
  const u16* qbase = qsT + chan0;
  u16* obase = attnT + chan0;
  float4 accs[2][6] = {}, acco[2][6] = {};
  float zs[2] = {}, zo[2] = {};
  for (int d = 0; d < 48; ++d) {
    const float p = pw[d];
    float qp[2], qn[2];
#pragma unroll
    for (int i = 0; i < 2; ++i) {
      const float qv = bf2f(qbase[(size_t)d * NTOK + i * 256]);
      const float f = pow_mag(fabsf(qv), p);
      qp[i] = (qv > 0.f) ? f : 0.f;
      qn[i] = (qv < 0.f) ? f : 0.f;
      zs[i] = fmaf(qp[i], kmL[d], zs[i]); zs[i] = fmaf(qn[i], kmL[d + 48], zs[i]);
      zo[i] = fmaf(qn[i], kmL[d], zo[i]); zo[i] = fmaf(qp[i], kmL[d + 48], zo[i]);
    }
#pragma unroll
    for (int e4 = 0; e4 < 6; ++e4) {
      const float4 kvA = *(const float4*)&kvmL[d][e4 * 4];
      const float4 kvB = *(const float4*)&kvmL[d + 48][e4 * 4];
      const float4 kvC = *(const float4*)&kvmL[d][24 + e4 * 4];
      const float4 kvD = *(const float4*)&kvmL[d + 48][24 + e4 * 4];
#pragma unroll
      for (int i = 0; i < 2; ++i) {
        accs[i][e4].x = fmaf(qp[i], kvA.x, fmaf(qn[i], kvB.x, accs[i][e4].x));
        accs[i][e4].y = fmaf(qp[i], kvA.y, fmaf(qn[i], kvB.y, accs[i][e4].y));
        accs[i][e4].z = fmaf(qp[i], kvA.z, fmaf(qn[i], kvB.z, accs[i][e4].z));
        accs[i][e4].w = fmaf(qp[i], kvA.w, fmaf(qn[i], kvB.w, accs[i][e4].w));
        acco[i][e4].x = fmaf(qn[i], kvC.x, fmaf(qp[i], kvD.x, acco[i][e4].x));
        acco[i][e4].y = fmaf(qn[i], kvC.y, fmaf(qp[i], kvD.y, acco[i][e4].y));
        acco[i][e4].z = fmaf(qn[i], kvC.z, fmaf(qp[i], kvD.z, acco[i][e4].z));
        acco[i][e4].w = fmaf(qn[i], kvC.w, fmaf(qp[i], kvD.w, acco[i][e4].w));
      }
    }
  }
#pragma unroll
  for (int i = 0; i < 2; ++i) {
    const float zsi = 1.0f / (zs[i] + 1e-6f);
    const float zoi = 1.0f / (zo[i] + 1e-6f);
#pragma unroll
    for (int e4 = 0; e4 < 6; ++e4) {
      const float4 s = accs[i][e4], o = acco[i][e4];
      obase[(size_t)(e4 * 4 + 0) * NTOK + i * 256]    = f2bf(s.x * zsi);
      obase[(size_t)(e4 * 4 + 1) * NTOK + i * 256]    = f2bf(s.y * zsi);
      obase[(size_t)(e4 * 4 + 2) * NTOK + i * 256]    = f2bf(s.z * zsi);
      obase[(size_t)(e4 * 4 + 3) * NTOK + i * 256]    = f2bf(s.w * zsi);
      obase[(size_t)(24 + e4 * 4 + 0) * NTOK + i * 256] = f2bf(o.x * zoi);
      obase[(size_t)(24 + e4 * 4 + 1) * NTOK + i * 256] = f2bf(o.y * zoi);
      obase[(size_t)(24 + e4 * 4 + 2) * NTOK + i * 256] = f2bf(o.z * zoi);
      obase[(size_t)(24 + e4 * 4 + 3) * NTOK + i * 256] = f2bf(o.w * zoi);
    }
  }
}

// ---------------- k4: 5x5 depthwise conv on vT + out2 = (attn + conv) * g ----------
__global__ __launch_bounds__(256) void k4_conv_combine(
    const u16* __restrict__ vT, const u16* __restrict__ gT,
    const void* __restrict__ dwc_w, const void* __restrict__ dwc_b,
    const int* __restrict__ flag,
    u16* __restrict__ attnT)
{
  const bool f32 = (*flag != 0);
  __shared__ float tile[20][128];
  const int bc = blockIdx.y;
  const int y0 = blockIdx.x * 16;
  const int t = threadIdx.x;
  const int d = bc % 48;
  float w[25];
#pragma unroll
  for (int i = 0; i < 25; ++i) w[i] = ldx1(dwc_w, d * 25 + i, f32);
  const float bias = ldx1(dwc_b, d, f32);
  const u16* vimg = vT + (size_t)bc * NTOK;
  for (int i = t; i < 20 * 128; i += 256) {
    const int r = i >> 7, xx = i & 127;
    const int gy = y0 + r - 2;
    tile[r][xx] = (gy >= 0 && gy < IMGH) ? bf2f(vimg[gy * IMGW + xx]) : 0.f;
  }
  __syncthreads();
  u16* abase = attnT + (size_t)bc * NTOK;
  const u16* gbase = gT + (size_t)bc * NTOK;
#pragma unroll
  for (int k = 0; k < 8; ++k) {
    const int px = t + k * 256;
    const int yy = px >> 7, xcol = px & 127;
    float acc = bias;
#pragma unroll
    for (int dy = 0; dy < 5; ++dy)
#pragma unroll
      for (int dx = 0; dx < 5; ++dx) {
        const int ux = xcol + dx - 2;
        const float val = (ux >= 0 && ux < IMGW) ? tile[yy + dy][ux] : 0.f;
        acc = fmaf(w[dy * 5 + dx], val, acc);
      }
    const int gidx = (y0 + yy) * IMGW + xcol;
    abase[gidx] = f2bf((bf2f(abase[gidx]) + acc) * bf2f(gbase[gidx]));
  }
}

// ---------------- k4b: transpose out2 channel-major -> token-major -----------------
__global__ __launch_bounds__(256) void k4b_transpose(
    const u16* __restrict__ src,   // [(b*384+c)][n]
    u16* __restrict__ dst)         // [(b*16384+n)][c]
{
  __shared__ u16 tile[64][68];
  const int b  = blockIdx.z;
  const int c0 = blockIdx.y * 64;
  const int n0 = blockIdx.x * 64;
  const int t = threadIdx.x;
  const int tr = t >> 4, tq = t & 15;
#pragma unroll
  for (int i = 0; i < 4; ++i) {
    const int r = tr + i * 16;     // c-row
    *(ushort4*)&tile[r][tq * 4] =
        *(const ushort4*)(src + ((size_t)(b * CDIM + c0 + r)) * NTOK + n0 + tq * 4);
  }
  __syncthreads();
#pragma unroll
  for (int i = 0; i < 4; ++i) {
    const int n = tr + i * 16;     // token-row
    const ushort4 vv = make_ushort4(tile[tq * 4 + 0][n], tile[tq * 4 + 1][n],
                                    tile[tq * 4 + 2][n], tile[tq * 4 + 3][n]);
    *(ushort4*)(dst + ((size_t)(b * NTOK + n0 + n)) * CDIM + c0 + tq * 4) = vv;
  }
}

// ---------------- k5: MFMA GEMM out2_tm @ Wproj + b -> d_out -----------------------
__global__ __launch_bounds__(256) void k5_mfma(
    const u16* __restrict__ A,     // [row=b*16384+n][c] bf16
    const u16* __restrict__ WpT,   // [c_out][c_in] bf16
    const void* __restrict__ bp, const int* __restrict__ flag,
    void* __restrict__ out)
{
  const bool f32 = (*flag != 0);
  __shared__ __align__(16) u16 Asm[128 * 64];
  __shared__ __align__(16) u16 Bsm[128 * 64];
  const int t = threadIdx.x;
  const int n0 = blockIdx.x * 128;  // 0..383
  const int m0 = blockIdx.y * 128;
  const int wave = t >> 6, lane = t & 63;
  const int wr = wave >> 1, wc = wave & 1;
  const int lm = lane & 15, lq = lane >> 4;

  f32x4 acc[4][4] = {};

  for (int k0 = 0; k0 < CDIM; k0 += 64) {
#pragma unroll
    for (int i = 0; i < 4; ++i) {
      const int chunk = t + i * 256;
      const int row = chunk >> 3, c8 = chunk & 7;
      const int ldsoff = row * 64 + ((c8 ^ (row & 7)) * 8);
      *(uint4*)&Asm[ldsoff] = *(const uint4*)(A + (size_t)(m0 + row) * CDIM + k0 + c8 * 8);
      *(uint4*)&Bsm[ldsoff] = *(const uint4*)(WpT + (size_t)(n0 + row) * CDIM + k0 + c8 * 8);
    }
    __syncthreads();
#pragma unroll
    for (int kh = 0; kh < 2; ++kh) {
      bf16x8 af[4], bfr[4];
#pragma unroll
      for (int r = 0; r < 4; ++r) {
        const int row = wr * 64 + r * 16 + lm;
        af[r] = *(const bf16x8*)&Asm[row * 64 + (((kh * 4 + lq) ^ (row & 7)) * 8)];
      }
#pragma unroll
      for (int cb = 0; cb < 4; ++cb) {
        const int row = wc * 64 + cb * 16 + lm;
        bfr[cb] = *(const bf16x8*)&Bsm[row * 64 + (((kh * 4 + lq) ^ (row & 7)) * 8)];
      }
#pragma unroll
      for (int r = 0; r < 4; ++r)
#pragma unroll
        for (int cb = 0; cb < 4; ++cb)
          acc[r][cb] = __builtin_amdgcn_mfma_f32_16x16x32_bf16(af[r], bfr[cb], acc[r][cb], 0, 0, 0);
    }
    __syncthreads();
  }
#pragma unroll
  for (int cb = 0; cb < 4; ++cb) {
    const int cg = n0 + wc * 64 + cb * 16 + lm;
    const float bb = ldx1(bp, cg, f32);
#pragma unroll
    for (int r = 0; r < 4; ++r) {
      const int rowtok = m0 + wr * 64 + r * 16 + lq * 4;   // global (B*N) row
      const f32x4 v = acc[r][cb];
#pragma unroll
      for (int reg = 0; reg < 4; ++reg) {
        const size_t o = (size_t)(rowtok + reg) * CDIM + cg;
        if (f32) ((float*)out)[o] = v[reg] + bb;
        else     ((u16*)out)[o]   = f2bf(v[reg] + bb);
      }
    }
  }
}

extern "C" void kernel_launch(void* const* d_in, const int* in_sizes, int n_in,
                              void* d_out, int out_size, void* d_ws, size_t ws_size,
                              hipStream_t stream) {
  const void* x       = d_in[0];
  const void* Wqg     = d_in[1];
  const void* Wkv     = d_in[2];
  const void* Wproj   = d_in[3];
  const void* bproj   = d_in[4];
  const void* pos_enc = d_in[5];
  const void* power_p = d_in[6];
  const void* scale_p = d_in[7];
  const void* dwc_w   = d_in[8];
  const void* dwc_b   = d_in[9];

  const size_t S = (size_t)NB * NTOK * CDIM;                 // 25,165,824
  const size_t stats_off   = 256;
  const size_t stats_bytes = (size_t)(32 * 96 + 32 * 96 * 48) * sizeof(float);
  const size_t w2t_elems = 1536 * 384, wpt_elems = 384 * 384;
  const size_t need = stats_off + stats_bytes + 3 * S * sizeof(u16)
                    + (w2t_elems + wpt_elems) * sizeof(u16);
  if (ws_size < need) return;

  int*   flag = (int*)d_ws;
  float* km   = (float*)((char*)d_ws + stats_off);
  float* kvm  = km + 32 * 96;
  u16* qsT = (u16*)((char*)d_ws + stats_off + stats_bytes);  // q/scale; later out2_tm
  u16* gT  = qsT + S;
  u16* ksT = gT + S;                                         // k feats; attn; out2
  u16* W2T = ksT + S;
  u16* WpT = W2T + w2t_elems;
  u16* vT  = (u16*)d_out;                                    // dead before k5 writes

  hipMemsetAsync(km, 0, stats_bytes, stream);

  k0_detect<<<1, 256, 0, stream>>>(x, flag);
  kprep<<<(int)((w2t_elems + wpt_elems + 255) / 256), 256, 0, stream>>>(
      Wqg, Wkv, Wproj, flag, W2T, WpT);
  k1_mfma<<<dim3(12, 512), 256, 0, stream>>>(x, W2T, pos_enc, scale_p, flag,
                                             qsT, gT, ksT, vT);
  k2_stats<<<dim3(32, 16), 256, 0, stream>>>(ksT, vT, power_p, flag, km, kvm);
  k3_attn<<<dim3(32, 32), 256, 0, stream>>>(qsT, ksT, km, kvm, power_p, flag);
  k4_conv_combine<<<dim3(8, 1536), 256, 0, stream>>>(vT, gT, dwc_w, dwc_b, flag, ksT);
  k4b_transpose<<<dim3(256, 6, 4), 256, 0, stream>>>(ksT, qsT);
  k5_mfma<<<dim3(3, 512), 256, 0, stream>>>(qsT, WpT, bproj, flag, d_out);
}